// Round 7
// baseline (4366.505 us; speedup 1.0000x reference)
//
#include <hip/hip_runtime.h>

// CUBA Spiking CNN, B=32, T=100.
// R3: conv2 via MFMA 16x16x32 f16 with scaled 2-way split (hi + 2^-12*lo),
// weight error ~2^-24|w| -> psp error ~1e-7 (R1-proven harmless scale).
// XOR-swizzled f16 spike tile in LDS; zero-skip on conv3/tc/rec/fc1 K-loops.

#define VTH 0.5f

// d_ws float offsets
#define W2P_OFF  0
#define W3P_OFF  73728
#define TCP_OFF  368640
#define RECP_OFF 565248
#define FC1P_OFF 630784
#define WS_FLOATS 663552

typedef __attribute__((ext_vector_type(8))) _Float16 half8v;
typedef __attribute__((ext_vector_type(4))) float f32x4;

__device__ inline unsigned short f2h_bits(float x) {
  union { _Float16 h; unsigned short u; } c; c.h = (_Float16)x; return c.u;
}
__device__ inline float h2f(unsigned short u) {
  union { unsigned short u; _Float16 h; } c; c.u = u; return (float)c.h;
}

__global__ __launch_bounds__(256) void prep_weights(
    const float* __restrict__ w2, const float* __restrict__ w3,
    const float* __restrict__ tcw, const float* __restrict__ recw,
    const float* __restrict__ fc1w, float* __restrict__ ws)
{
  int idx = blockIdx.x * 256 + threadIdx.x;
  if (idx < W3P_OFF) {
    // f16 hi/lo fragments for 16x16x32 MFMA B operand.
    // frag = (kt*8 + nt)*2 + half ; per frag 1024B = 256 dwords.
    // element j of lane: oc = nt*16 + (lane&15); k = kt*32 + (lane>>4)*8 + j.
    // lo half stores f16((w - f16(w)) * 4096)  [exact pow2 scale].
    int frag = idx >> 8, r = idx & 255;
    int lane = r >> 2, dw = r & 3;
    int half = frag & 1, nt = (frag >> 1) & 7, kt = frag >> 4;
    unsigned out = 0;
    #pragma unroll
    for (int j2 = 0; j2 < 2; ++j2) {
      int j = dw * 2 + j2;
      int oc = nt * 16 + (lane & 15);
      int k = kt * 32 + ((lane >> 4) << 3) + j;
      int c = k & 63, tap = k >> 6;
      float w = w2[(oc * 64 + c) * 9 + tap];
      unsigned short hb = f2h_bits(w);
      unsigned short bits = half ? f2h_bits((w - h2f(hb)) * 4096.f) : hb;
      out |= ((unsigned)bits) << (16 * j2);
    }
    ((unsigned*)ws)[idx] = out;
  } else if (idx < TCP_OFF) {
    int i = idx - W3P_OFF;
    int r = i & 3, ocq = (i >> 2) & 63, k = i >> 8;
    int oc = ocq * 4 + r, c = k & 127, pos9 = k >> 7;
    ws[idx] = w3[(oc * 128 + c) * 9 + pos9];
  } else if (idx < RECP_OFF) {
    int i = idx - TCP_OFF;
    int r = i & 3, dq = (i >> 2) & 63, k = i >> 8;
    int d = dq * 4 + r, c = k & 255, kk = k >> 8;
    ws[idx] = tcw[(kk * 256 + d) * 256 + c];
  } else if (idx < FC1P_OFF) {
    int i = idx - RECP_OFF;
    int r = i & 3, dq = (i >> 2) & 63, c = i >> 8;
    ws[idx] = recw[(dq * 4 + r) * 256 + c];
  } else if (idx < WS_FLOATS) {
    int i = idx - FC1P_OFF;
    int r = i & 3, dq = (i >> 2) & 31, c = i >> 7;
    ws[idx] = fc1w[(dq * 4 + r) * 256 + c];
  }
}

__global__ __launch_bounds__(1024, 4) void snn_main(
    const float* __restrict__ input,   // [32,1,10,10,100]
    const float* __restrict__ w1g,     // [64,1,3,3]
    const float* __restrict__ b1g,     // [64]
    const float* __restrict__ b2g,     // [128]
    const float* __restrict__ b3g,     // [256]
    const float* __restrict__ tcbg,    // [3,256]
    const float* __restrict__ recbg,   // [256]
    const float* __restrict__ fc1bg,   // [128]
    const float* __restrict__ fc2wg,   // [2,128]
    const float* __restrict__ tswg,    // [100]
    const float* __restrict__ maskg,   // [32,128]
    const float* __restrict__ c1sg, const float* __restrict__ c2sg,
    const float* __restrict__ c3sg, const float* __restrict__ tcsg,
    const float* __restrict__ rsg,  const float* __restrict__ fsg,
    const float* __restrict__ ws,  float* __restrict__ out)
{
  const half8v* w2h  = (const half8v*)ws;              // 288 frags x 64 lanes
  const float4* w3p  = (const float4*)(ws + W3P_OFF);
  const float4* tcp  = (const float4*)(ws + TCP_OFF);
  const float4* recp = (const float4*)(ws + RECP_OFF);
  const float4* fc1p = (const float4*)(ws + FC1P_OFF);

  const int b   = blockIdx.x;
  const int tid = threadIdx.x;
  const int wv  = tid >> 6;
  const int ln  = tid & 63;

  __shared__ __align__(16) float scratch[4096];        // 16KB reduce scratch
  __shared__ __align__(16) unsigned short s1b[84 * 64];// f16 spikes, rows 64+ zero
  __shared__ unsigned short s2b[36 * 128];             // conv2 spikes f16
  __shared__ float p2f[1152];                          // [9][128] pooled (f32)
  __shared__ float xt[100];
  __shared__ float histf[768];                         // 3 x [256] flat-spike ring
  __shared__ float s4v[256];
  __shared__ float c3cur[256], c3vol[256], c3sp[256];
  __shared__ float tccur[256], tcvol[256], tcsp[256];
  __shared__ float rcur[256],  rvol[256],  rsp[256];
  __shared__ float fcur[128],  fvol[128],  fsp[128];
  __shared__ float b3L[256], tcbL[768], recbL[256], fc1bL[128];
  __shared__ float fc2wL[256], maskL[128], tswL[100], b2L[128];
  __shared__ float accv[2];
  __shared__ float wpart[2][2];

  // ---------------- init ----------------
  const int co   = ln;
  const int pos0 = wv;              // 0..15
  float w1r[9];
  #pragma unroll
  for (int k = 0; k < 9; ++k) w1r[k] = w1g[co * 9 + k];
  const float b1r = b1g[co];
  float sp1[4], cur1[4], vol1[4];
  #pragma unroll
  for (int j = 0; j < 4; ++j) {
    int pos = pos0 + 16 * j;
    sp1[j]  = c1sg[((0 * 32 + b) * 64 + co) * 64 + pos];
    cur1[j] = c1sg[((1 * 32 + b) * 64 + co) * 64 + pos];
    vol1[j] = c1sg[((2 * 32 + b) * 64 + co) * 64 + pos];
  }

  // conv2 MFMA tiling: waves 0-7: nt=wv, Mtiles {0,1}; waves 8-15: nt=wv-8,
  // Mtile {2} only (rows 32..47, 36..47 padded).
  const int grpB  = (wv < 8);
  const int nt2 = grpB ? wv : (wv - 8);
  const int mtA = grpB ? 0 : 2;
  const int mtB = 1;                 // only used when grpB
  const int oc2 = nt2 * 16 + (ln & 15);
  int pybA, pybB;
  {
    int pA = mtA * 16 + (ln & 15);
    int pB = mtB * 16 + (ln & 15);
    pybA = (pA < 36) ? ((pA / 6) * 8 + (pA % 6)) : 64;
    pybB = (pB / 6) * 8 + (pB % 6);
  }
  float cur2[2][4], vol2[2][4];
  #pragma unroll
  for (int m = 0; m < 2; ++m) {
    int mt = m ? mtB : mtA;
    bool use = (m == 0) || grpB;
    #pragma unroll
    for (int r = 0; r < 4; ++r) {
      int p = mt * 16 + ((ln >> 4) << 2) + r;
      if (use && p < 36) {
        cur2[m][r] = c2sg[((1 * 32 + b) * 128 + oc2) * 36 + p];
        vol2[m][r] = c2sg[((2 * 32 + b) * 128 + oc2) * 36 + p];
      } else { cur2[m][r] = 0.f; vol2[m][r] = 0.f; }
    }
  }

  if (tid < 256) {
    c3sp[tid]  = c3sg[(0 * 32 + b) * 256 + tid];
    c3cur[tid] = c3sg[(1 * 32 + b) * 256 + tid];
    c3vol[tid] = c3sg[(2 * 32 + b) * 256 + tid];
    tcsp[tid]  = tcsg[(0 * 32 + b) * 256 + tid];
    tccur[tid] = tcsg[(1 * 32 + b) * 256 + tid];
    tcvol[tid] = tcsg[(2 * 32 + b) * 256 + tid];
    rsp[tid]   = rsg[(0 * 32 + b) * 256 + tid];
    rcur[tid]  = rsg[(1 * 32 + b) * 256 + tid];
    rvol[tid]  = rsg[(2 * 32 + b) * 256 + tid];
    b3L[tid]   = b3g[tid];
    recbL[tid] = recbg[tid];
    tcbL[tid]       = tcbg[tid];
    tcbL[256 + tid] = tcbg[256 + tid];
    tcbL[512 + tid] = tcbg[512 + tid];
    histf[tid] = 0.f; histf[256 + tid] = 0.f; histf[512 + tid] = 0.f;
  }
  if (tid < 128) {
    fsp[tid]   = fsg[(0 * 32 + b) * 128 + tid];
    fcur[tid]  = fsg[(1 * 32 + b) * 128 + tid];
    fvol[tid]  = fsg[(2 * 32 + b) * 128 + tid];
    fc1bL[tid] = fc1bg[tid];
    maskL[tid] = maskg[b * 128 + tid];
    b2L[tid]   = b2g[tid];
    fc2wL[tid]       = fc2wg[tid];
    fc2wL[128 + tid] = fc2wg[128 + tid];
  }
  if (tid < 100) tswL[tid] = tswg[tid];
  if (tid < 640) ((unsigned*)s1b)[64 * 32 + tid] = 0u;   // zero pad rows 64..83
  if (tid == 0) { accv[0] = 0.f; accv[1] = 0.f; }
  __syncthreads();

  // ---------------- time loop ----------------
  for (int t = 0; t < 100; ++t) {
    const int tm3 = t % 3;

    // phase 0: stage x_t
    if (tid < 100) xt[tid] = input[(b * 100 + tid) * 100 + t];
    __syncthreads();

    // phase 1: conv1 + LIF1 -> s1b (f16 bits, XOR-swizzled rows)
    #pragma unroll
    for (int j = 0; j < 4; ++j) {
      int pos = pos0 + 16 * j;
      int y = pos >> 3, x = pos & 7;
      float psp = b1r;
      #pragma unroll
      for (int kk = 0; kk < 9; ++kk) {
        int ky = kk / 3, kx = kk - ky * 3;
        psp = fmaf(xt[(y + ky) * 10 + x + kx], w1r[kk], psp);
      }
      float cur = 0.5f * cur1[j] + psp;
      float vol = 0.75f * vol1[j] * (1.f - sp1[j]) + cur;
      float sp  = (vol > VTH) ? 1.f : 0.f;
      cur1[j] = cur; vol1[j] = vol; sp1[j] = sp;
      unsigned short bits = (vol > VTH) ? (unsigned short)0x3C00 : (unsigned short)0;
      int byte = ((pos << 7) + (co << 1)) ^ ((pos & 7) << 4);
      *(unsigned short*)((char*)s1b + byte) = bits;
    }
    __syncthreads();

    // phase 2: conv2 via MFMA 16x16x32 f16 (scaled hi/lo split)
    {
      f32x4 acchA = {0,0,0,0}, acclA = {0,0,0,0};
      f32x4 acchB = {0,0,0,0}, acclB = {0,0,0,0};
      const int lnq16 = (ln >> 4) << 4;
      if (grpB) {
        #pragma unroll
        for (int kt = 0; kt < 18; ++kt) {
          const int tap = kt >> 1;
          const int dpos = (tap / 3) * 8 + (tap % 3);
          const int c0b = ((kt & 1) << 6) + lnq16;
          int posA = pybA + dpos, posB = pybB + dpos;
          int abA = ((posA << 7) + c0b) ^ ((posA & 7) << 4);
          int abB = ((posB << 7) + c0b) ^ ((posB & 7) << 4);
          half8v a0 = *(const half8v*)((const char*)s1b + abA);
          half8v a1 = *(const half8v*)((const char*)s1b + abB);
          half8v bh = w2h[(((kt << 3) + nt2) << 1) * 64 + ln];
          half8v bl = w2h[((((kt << 3) + nt2) << 1) + 1) * 64 + ln];
          acchA = __builtin_amdgcn_mfma_f32_16x16x32_f16(a0, bh, acchA, 0, 0, 0);
          acclA = __builtin_amdgcn_mfma_f32_16x16x32_f16(a0, bl, acclA, 0, 0, 0);
          acchB = __builtin_amdgcn_mfma_f32_16x16x32_f16(a1, bh, acchB, 0, 0, 0);
          acclB = __builtin_amdgcn_mfma_f32_16x16x32_f16(a1, bl, acclB, 0, 0, 0);
        }
      } else {
        #pragma unroll
        for (int kt = 0; kt < 18; ++kt) {
          const int tap = kt >> 1;
          const int dpos = (tap / 3) * 8 + (tap % 3);
          const int c0b = ((kt & 1) << 6) + lnq16;
          int posA = pybA + dpos;
          int abA = ((posA << 7) + c0b) ^ ((posA & 7) << 4);
          half8v a0 = *(const half8v*)((const char*)s1b + abA);
          half8v bh = w2h[(((kt << 3) + nt2) << 1) * 64 + ln];
          half8v bl = w2h[((((kt << 3) + nt2) << 1) + 1) * 64 + ln];
          acchA = __builtin_amdgcn_mfma_f32_16x16x32_f16(a0, bh, acchA, 0, 0, 0);
          acclA = __builtin_amdgcn_mfma_f32_16x16x32_f16(a0, bl, acclA, 0, 0, 0);
        }
      }
      // LIF2 + spike store (C layout: col=lane&15 -> pixel? no: col -> oc? )
      // C/D: col = lane&15 (matches A's M rows via our mapping), row idx r.
      float bias2 = b2L[oc2];
      #pragma unroll
      for (int m = 0; m < 2; ++m) {
        if (m == 1 && !grpB) break;
        int mt = m ? mtB : mtA;
        #pragma unroll
        for (int r = 0; r < 4; ++r) {
          int p = mt * 16 + ((ln >> 4) << 2) + r;
          if (p < 36) {
            float hi = m ? acchB[r] : acchA[r];
            float lo = m ? acclB[r] : acclA[r];
            float psp = hi + 0.000244140625f * lo + bias2;
            float spo = (vol2[m][r] > VTH) ? 1.f : 0.f;
            float cur = 0.5f * cur2[m][r] + psp;
            float vol = 0.75f * vol2[m][r] * (1.f - spo) + cur;
            cur2[m][r] = cur; vol2[m][r] = vol;
            s2b[p * 128 + oc2] = (vol > VTH) ? (unsigned short)0x3C00 : (unsigned short)0;
          }
        }
      }
    }
    __syncthreads();

    // phase 3: avgpool 2x2 (6x6 -> 3x3) -> p2f[pp*128+c]
    {
      int c = tid & 127, pp = tid >> 7;   // pp 0..7
      int sy = (pp / 3) * 2, sx = (pp % 3) * 2;
      float v = h2f(s2b[(sy * 6 + sx) * 128 + c]) + h2f(s2b[(sy * 6 + sx + 1) * 128 + c])
              + h2f(s2b[((sy + 1) * 6 + sx) * 128 + c]) + h2f(s2b[((sy + 1) * 6 + sx + 1) * 128 + c]);
      p2f[pp * 128 + c] = 0.25f * v;
      if (tid < 128) {
        float v8 = h2f(s2b[(4 * 6 + 4) * 128 + c]) + h2f(s2b[(4 * 6 + 5) * 128 + c])
                 + h2f(s2b[(5 * 6 + 4) * 128 + c]) + h2f(s2b[(5 * 6 + 5) * 128 + c]);
        p2f[8 * 128 + c] = 0.25f * v8;
      }
    }
    __syncthreads();

    // phase 4: conv3 partials (K=1152 split 16 ways, 4 oc/thread, zero-skip)
    {
      int ocq = tid & 63, ks = tid >> 6;
      float4 a = {0.f, 0.f, 0.f, 0.f};
      const float4* wrow = w3p + (ks * 72) * 64 + ocq;
      const float* prow = p2f + ks * 72;
      #pragma unroll 8
      for (int i = 0; i < 72; ++i) {
        float pv = prow[i];
        if (pv != 0.f) {
          float4 w = wrow[i * 64];
          a.x = fmaf(pv, w.x, a.x); a.y = fmaf(pv, w.y, a.y);
          a.z = fmaf(pv, w.z, a.z); a.w = fmaf(pv, w.w, a.w);
        }
      }
      ((float4*)scratch)[tid] = a;
    }
    __syncthreads();
    // phase 5: conv3 reduce + LIF3 -> hist[t%3]
    if (tid < 256) {
      int d = tid;
      float s = b3L[d];
      #pragma unroll
      for (int ks = 0; ks < 16; ++ks) s += scratch[ks * 256 + d];
      float cur = 0.5f * c3cur[d] + s;
      float vol = 0.75f * c3vol[d] * (1.f - c3sp[d]) + cur;
      float sp  = (vol > VTH) ? 1.f : 0.f;
      c3cur[d] = cur; c3vol[d] = vol; c3sp[d] = sp;
      histf[tm3 * 256 + d] = sp;
    }
    __syncthreads();

    // phase 6: temporal-conv partials (K=768 split 16 ways, zero-skip)
    {
      int dq = tid & 63, ks = tid >> 6;
      float4 a = {0.f, 0.f, 0.f, 0.f};
      const float4* wrow = tcp + (ks * 48) * 64 + dq;
      #pragma unroll 8
      for (int i = 0; i < 48; ++i) {
        int k = ks * 48 + i;
        int kk = k >> 8;
        int vv = tm3 + 1 + kk; if (vv >= 3) vv -= 3;
        float hv = histf[(vv << 8) + (k & 255)];
        if (hv != 0.f) {
          float4 w = wrow[i * 64];
          a.x = fmaf(hv, w.x, a.x); a.y = fmaf(hv, w.y, a.y);
          a.z = fmaf(hv, w.z, a.z); a.w = fmaf(hv, w.w, a.w);
        }
      }
      ((float4*)scratch)[tid] = a;
    }
    __syncthreads();
    // phase 7: tc reduce + masked bias + LIF4 -> s4v
    if (tid < 256) {
      int d = tid;
      float s = 0.f;
      #pragma unroll
      for (int ks = 0; ks < 16; ++ks) s += scratch[ks * 256 + d];
      #pragma unroll
      for (int kk = 0; kk < 3; ++kk)
        if (t >= 2 - kk) s += tcbL[kk * 256 + d];
      float cur = 0.5f * tccur[d] + s;
      float vol = 0.75f * tcvol[d] * (1.f - tcsp[d]) + cur;
      float sp  = (vol > VTH) ? 1.f : 0.f;
      tccur[d] = cur; tcvol[d] = vol; tcsp[d] = sp;
      s4v[d] = sp;
    }
    __syncthreads();

    // phase 8: recurrent partials (reads s5_prev = rsp, zero-skip)
    {
      int dq = tid & 63, ks = tid >> 6;
      float4 a = {0.f, 0.f, 0.f, 0.f};
      const float4* wrow = recp + (ks * 16) * 64 + dq;
      const float* hr = rsp + ks * 16;
      #pragma unroll
      for (int i = 0; i < 16; ++i) {
        float hv = hr[i];
        if (hv != 0.f) {
          float4 w = wrow[i * 64];
          a.x = fmaf(hv, w.x, a.x); a.y = fmaf(hv, w.y, a.y);
          a.z = fmaf(hv, w.z, a.z); a.w = fmaf(hv, w.w, a.w);
        }
      }
      ((float4*)scratch)[tid] = a;
    }
    __syncthreads();
    // phase 9: rec reduce + LIF5 -> rsp (= s5)
    if (tid < 256) {
      int d = tid;
      float s = s4v[d] + recbL[d];
      #pragma unroll
      for (int ks = 0; ks < 16; ++ks) s += scratch[ks * 256 + d];
      float cur = 0.5f * rcur[d] + s;
      float vol = 0.75f * rvol[d] * (1.f - rsp[d]) + cur;
      float sp  = (vol > VTH) ? 1.f : 0.f;
      rcur[d] = cur; rvol[d] = vol; rsp[d] = sp;
    }
    __syncthreads();

    // phase 10: fc1 partials (K=256 split 32 ways, zero-skip)
    {
      int dq = tid & 31, ks = tid >> 5;
      float4 a = {0.f, 0.f, 0.f, 0.f};
      const float4* wrow = fc1p + (ks * 8) * 32 + dq;
      const float* hr = rsp + ks * 8;
      #pragma unroll
      for (int i = 0; i < 8; ++i) {
        float hv = hr[i];
        if (hv != 0.f) {
          float4 w = wrow[i * 32];
          a.x = fmaf(hv, w.x, a.x); a.y = fmaf(hv, w.y, a.y);
          a.z = fmaf(hv, w.z, a.z); a.w = fmaf(hv, w.w, a.w);
        }
      }
      ((float4*)scratch)[tid] = a;
    }
    __syncthreads();
    // phase 11: fc1 reduce + dropout-mask LIF6 + fc2 partial reduce
    if (tid < 128) {
      int d = tid;
      float s = fc1bL[d];
      #pragma unroll
      for (int ks = 0; ks < 32; ++ks) s += scratch[ks * 128 + d];
      float cur = (0.5f * fcur[d] + s) * maskL[d];
      float vol = 0.75f * fvol[d] * (1.f - fsp[d]) + cur;
      float sp  = (vol > VTH) ? 1.f : 0.f;
      fcur[d] = cur; fvol[d] = vol; fsp[d] = sp;
      float v0 = sp * fc2wL[d];
      float v1 = sp * fc2wL[128 + d];
      #pragma unroll
      for (int off = 32; off > 0; off >>= 1) {
        v0 += __shfl_down(v0, off);
        v1 += __shfl_down(v1, off);
      }
      if ((tid & 63) == 0) { wpart[tid >> 6][0] = v0; wpart[tid >> 6][1] = v1; }
    }
    __syncthreads();
    if (tid == 0) {
      float wt = tswL[t];
      accv[0] += wt * (wpart[0][0] + wpart[1][0]);
      accv[1] += wt * (wpart[0][1] + wpart[1][1]);
    }
  }
  __syncthreads();
  if (tid < 2) out[b * 2 + tid] = accv[tid];
}

extern "C" void kernel_launch(void* const* d_in, const int* in_sizes, int n_in,
                              void* d_out, int out_size, void* d_ws, size_t ws_size,
                              hipStream_t stream) {
  const float* input = (const float*)d_in[0];
  const float* w1    = (const float*)d_in[1];
  const float* b1    = (const float*)d_in[2];
  const float* w2    = (const float*)d_in[3];
  const float* b2    = (const float*)d_in[4];
  const float* w3    = (const float*)d_in[5];
  const float* b3    = (const float*)d_in[6];
  const float* tcw   = (const float*)d_in[7];
  const float* tcb   = (const float*)d_in[8];
  const float* recw  = (const float*)d_in[9];
  const float* recb  = (const float*)d_in[10];
  const float* fc1w  = (const float*)d_in[11];
  const float* fc1b  = (const float*)d_in[12];
  const float* fc2w  = (const float*)d_in[13];
  const float* tsw   = (const float*)d_in[14];
  const float* mask  = (const float*)d_in[15];
  const float* c1s   = (const float*)d_in[16];
  const float* c2s   = (const float*)d_in[17];
  const float* c3s   = (const float*)d_in[18];
  const float* tcs   = (const float*)d_in[19];
  const float* rs    = (const float*)d_in[20];
  const float* fs    = (const float*)d_in[21];
  float* ws   = (float*)d_ws;
  float* outp = (float*)d_out;

  prep_weights<<<WS_FLOATS / 256, 256, 0, stream>>>(w2, w3, tcw, recw, fc1w, ws);
  snn_main<<<32, 1024, 0, stream>>>(input, w1, b1, b2, b3, tcb, recb, fc1b,
                                    fc2w, tsw, mask, c1s, c2s, c3s, tcs, rs, fs,
                                    ws, outp);
}

// Round 8
// 1956.865 us; speedup vs baseline: 2.2314x; 2.2314x over previous
//
#include <hip/hip_runtime.h>

// CUBA Spiking CNN, B=32, T=100.
// R8: two-stage cross-CU pipeline. Blocks 0-31: conv1+conv2(MFMA f16 split)+pool,
// publish exact-f16 pooled activations to d_ws with agent-scope release flags.
// Blocks 32-63: conv3/tc/rec/fc1/fc2 with ballot-compacted branch-free sparse
// weight streaming. Fallback to R7 monolithic kernel if ws_size too small.

#define VTH 0.5f

// d_ws float offsets
#define W2P_OFF  0
#define W3P_OFF  73728
#define TCP_OFF  368640
#define RECP_OFF 565248
#define FC1P_OFF 630784
#define WS_FLOATS 663552
#define P2F_DW_OFF   WS_FLOATS                 // p2f stream, 576 dwords per (b,t)
#define P2F_DWORDS   (32 * 100 * 576)
#define FLAG_DW_OFF  (P2F_DW_OFF + P2F_DWORDS)
#define FLAGS_N      (32 * 100)
#define WS_NEED_BYTES ((size_t)(FLAG_DW_OFF + FLAGS_N) * 4)

typedef __attribute__((ext_vector_type(8))) _Float16 half8v;
typedef __attribute__((ext_vector_type(4))) float f32x4;

__device__ inline unsigned short f2h_bits(float x) {
  union { _Float16 h; unsigned short u; } c; c.h = (_Float16)x; return c.u;
}
__device__ inline float h2f(unsigned short u) {
  union { unsigned short u; _Float16 h; } c; c.u = u; return (float)c.h;
}

__global__ __launch_bounds__(256) void prep_weights(
    const float* __restrict__ w2, const float* __restrict__ w3,
    const float* __restrict__ tcw, const float* __restrict__ recw,
    const float* __restrict__ fc1w, float* __restrict__ ws)
{
  int idx = blockIdx.x * 256 + threadIdx.x;
  if (idx < W3P_OFF) {
    // f16 hi/lo fragments for 16x16x32 MFMA B operand.
    int frag = idx >> 8, r = idx & 255;
    int lane = r >> 2, dw = r & 3;
    int half = frag & 1, nt = (frag >> 1) & 7, kt = frag >> 4;
    unsigned out = 0;
    #pragma unroll
    for (int j2 = 0; j2 < 2; ++j2) {
      int j = dw * 2 + j2;
      int oc = nt * 16 + (lane & 15);
      int k = kt * 32 + ((lane >> 4) << 3) + j;
      int c = k & 63, tap = k >> 6;
      float w = w2[(oc * 64 + c) * 9 + tap];
      unsigned short hb = f2h_bits(w);
      unsigned short bits = half ? f2h_bits((w - h2f(hb)) * 4096.f) : hb;
      out |= ((unsigned)bits) << (16 * j2);
    }
    ((unsigned*)ws)[idx] = out;
  } else if (idx < TCP_OFF) {
    int i = idx - W3P_OFF;
    int r = i & 3, ocq = (i >> 2) & 63, k = i >> 8;
    int oc = ocq * 4 + r, c = k & 127, pos9 = k >> 7;
    ws[idx] = w3[(oc * 128 + c) * 9 + pos9];
  } else if (idx < RECP_OFF) {
    int i = idx - TCP_OFF;
    int r = i & 3, dq = (i >> 2) & 63, k = i >> 8;
    int d = dq * 4 + r, c = k & 255, kk = k >> 8;
    ws[idx] = tcw[(kk * 256 + d) * 256 + c];
  } else if (idx < FC1P_OFF) {
    int i = idx - RECP_OFF;
    int r = i & 3, dq = (i >> 2) & 63, c = i >> 8;
    ws[idx] = recw[(dq * 4 + r) * 256 + c];
  } else if (idx < WS_FLOATS) {
    int i = idx - FC1P_OFF;
    int r = i & 3, dq = (i >> 2) & 31, c = i >> 7;
    ws[idx] = fc1w[(dq * 4 + r) * 256 + c];
  }
}

__global__ __launch_bounds__(256) void zero_flags(float* __restrict__ ws) {
  int i = blockIdx.x * 256 + threadIdx.x;
  if (i < FLAGS_N) ((unsigned*)ws)[FLAG_DW_OFF + i] = 0u;
}

// ---------------------------------------------------------------------------
// R8 pipelined kernel: 64 blocks. 0-31 = stage1 (conv1/conv2/pool producer),
// 32-63 = stage2 (conv3/tc/rec/fc1/fc2 consumer).
// ---------------------------------------------------------------------------
__global__ __launch_bounds__(1024, 4) void snn_pipe(
    const float* __restrict__ input, const float* __restrict__ w1g,
    const float* __restrict__ b1g, const float* __restrict__ b2g,
    const float* __restrict__ b3g, const float* __restrict__ tcbg,
    const float* __restrict__ recbg, const float* __restrict__ fc1bg,
    const float* __restrict__ fc2wg, const float* __restrict__ tswg,
    const float* __restrict__ maskg,
    const float* __restrict__ c1sg, const float* __restrict__ c2sg,
    const float* __restrict__ c3sg, const float* __restrict__ tcsg,
    const float* __restrict__ rsg, const float* __restrict__ fsg,
    float* __restrict__ ws, float* __restrict__ out)
{
  const int tid = threadIdx.x;
  const int wv  = tid >> 6;
  const int ln  = tid & 63;
  unsigned* p2g   = (unsigned*)ws + P2F_DW_OFF;
  unsigned* flags = (unsigned*)ws + FLAG_DW_OFF;

  if (blockIdx.x < 32) {
    // ======================= STAGE 1: conv1 + conv2 + pool ==================
    const int b = blockIdx.x;
    const half8v* w2h = (const half8v*)ws;

    __shared__ float xt[100];
    __shared__ __align__(16) unsigned short s1b[84 * 64];
    __shared__ unsigned short s2b[36 * 128];
    __shared__ float b2L[128];

    const int co = ln, pos0 = wv;
    float w1r[9];
    #pragma unroll
    for (int k = 0; k < 9; ++k) w1r[k] = w1g[co * 9 + k];
    const float b1r = b1g[co];
    float sp1[4], cur1[4], vol1[4];
    #pragma unroll
    for (int j = 0; j < 4; ++j) {
      int pos = pos0 + 16 * j;
      sp1[j]  = c1sg[((0 * 32 + b) * 64 + co) * 64 + pos];
      cur1[j] = c1sg[((1 * 32 + b) * 64 + co) * 64 + pos];
      vol1[j] = c1sg[((2 * 32 + b) * 64 + co) * 64 + pos];
    }
    const int grpB = (wv < 8);
    const int nt2 = grpB ? wv : (wv - 8);
    const int mtA = grpB ? 0 : 2;
    const int mtB = 1;
    const int oc2 = nt2 * 16 + (ln & 15);
    int pybA, pybB;
    {
      int pA = mtA * 16 + (ln & 15);
      int pB = mtB * 16 + (ln & 15);
      pybA = (pA < 36) ? ((pA / 6) * 8 + (pA % 6)) : 64;
      pybB = (pB / 6) * 8 + (pB % 6);
    }
    float cur2[2][4], vol2[2][4];
    #pragma unroll
    for (int m = 0; m < 2; ++m) {
      int mt = m ? mtB : mtA;
      bool use = (m == 0) || grpB;
      #pragma unroll
      for (int r = 0; r < 4; ++r) {
        int p = mt * 16 + ((ln >> 4) << 2) + r;
        if (use && p < 36) {
          cur2[m][r] = c2sg[((1 * 32 + b) * 128 + oc2) * 36 + p];
          vol2[m][r] = c2sg[((2 * 32 + b) * 128 + oc2) * 36 + p];
        } else { cur2[m][r] = 0.f; vol2[m][r] = 0.f; }
      }
    }
    if (tid < 128) b2L[tid] = b2g[tid];
    if (tid < 640) ((unsigned*)s1b)[64 * 32 + tid] = 0u;   // zero pad rows 64..83
    __syncthreads();

    for (int t = 0; t < 100; ++t) {
      if (tid < 100) xt[tid] = input[(b * 100 + tid) * 100 + t];
      __syncthreads();

      // conv1 + LIF1
      #pragma unroll
      for (int j = 0; j < 4; ++j) {
        int pos = pos0 + 16 * j;
        int y = pos >> 3, x = pos & 7;
        float psp = b1r;
        #pragma unroll
        for (int kk = 0; kk < 9; ++kk) {
          int ky = kk / 3, kx = kk - ky * 3;
          psp = fmaf(xt[(y + ky) * 10 + x + kx], w1r[kk], psp);
        }
        float cur = 0.5f * cur1[j] + psp;
        float vol = 0.75f * vol1[j] * (1.f - sp1[j]) + cur;
        float sp  = (vol > VTH) ? 1.f : 0.f;
        cur1[j] = cur; vol1[j] = vol; sp1[j] = sp;
        unsigned short bits = (vol > VTH) ? (unsigned short)0x3C00 : (unsigned short)0;
        int byte = ((pos << 7) + (co << 1)) ^ ((pos & 7) << 4);
        *(unsigned short*)((char*)s1b + byte) = bits;
      }
      __syncthreads();

      // conv2 MFMA (f16 scaled hi/lo split)
      {
        f32x4 acchA = {0,0,0,0}, acclA = {0,0,0,0};
        f32x4 acchB = {0,0,0,0}, acclB = {0,0,0,0};
        const int lnq16 = (ln >> 4) << 4;
        if (grpB) {
          #pragma unroll
          for (int kt = 0; kt < 18; ++kt) {
            const int tap = kt >> 1;
            const int dpos = (tap / 3) * 8 + (tap % 3);
            const int c0b = ((kt & 1) << 6) + lnq16;
            int posA = pybA + dpos, posB = pybB + dpos;
            int abA = ((posA << 7) + c0b) ^ ((posA & 7) << 4);
            int abB = ((posB << 7) + c0b) ^ ((posB & 7) << 4);
            half8v a0 = *(const half8v*)((const char*)s1b + abA);
            half8v a1 = *(const half8v*)((const char*)s1b + abB);
            half8v bh = w2h[(((kt << 3) + nt2) << 1) * 64 + ln];
            half8v bl = w2h[((((kt << 3) + nt2) << 1) + 1) * 64 + ln];
            acchA = __builtin_amdgcn_mfma_f32_16x16x32_f16(a0, bh, acchA, 0, 0, 0);
            acclA = __builtin_amdgcn_mfma_f32_16x16x32_f16(a0, bl, acclA, 0, 0, 0);
            acchB = __builtin_amdgcn_mfma_f32_16x16x32_f16(a1, bh, acchB, 0, 0, 0);
            acclB = __builtin_amdgcn_mfma_f32_16x16x32_f16(a1, bl, acclB, 0, 0, 0);
          }
        } else {
          #pragma unroll
          for (int kt = 0; kt < 18; ++kt) {
            const int tap = kt >> 1;
            const int dpos = (tap / 3) * 8 + (tap % 3);
            const int c0b = ((kt & 1) << 6) + lnq16;
            int posA = pybA + dpos;
            int abA = ((posA << 7) + c0b) ^ ((posA & 7) << 4);
            half8v a0 = *(const half8v*)((const char*)s1b + abA);
            half8v bh = w2h[(((kt << 3) + nt2) << 1) * 64 + ln];
            half8v bl = w2h[((((kt << 3) + nt2) << 1) + 1) * 64 + ln];
            acchA = __builtin_amdgcn_mfma_f32_16x16x32_f16(a0, bh, acchA, 0, 0, 0);
            acclA = __builtin_amdgcn_mfma_f32_16x16x32_f16(a0, bl, acclA, 0, 0, 0);
          }
        }
        float bias2 = b2L[oc2];
        #pragma unroll
        for (int m = 0; m < 2; ++m) {
          if (m == 1 && !grpB) break;
          int mt = m ? mtB : mtA;
          #pragma unroll
          for (int r = 0; r < 4; ++r) {
            int p = mt * 16 + ((ln >> 4) << 2) + r;
            if (p < 36) {
              float hi = m ? acchB[r] : acchA[r];
              float lo = m ? acclB[r] : acclA[r];
              float psp = hi + 0.000244140625f * lo + bias2;
              float spo = (vol2[m][r] > VTH) ? 1.f : 0.f;
              float cur = 0.5f * cur2[m][r] + psp;
              float vol = 0.75f * vol2[m][r] * (1.f - spo) + cur;
              cur2[m][r] = cur; vol2[m][r] = vol;
              s2b[p * 128 + oc2] = (vol > VTH) ? (unsigned short)0x3C00 : (unsigned short)0;
            }
          }
        }
      }
      __syncthreads();

      // pool + publish exact f16 p2f (576 dwords)
      if (tid < 576) {
        int pp = tid >> 6, c0 = 2 * (tid & 63);
        int sy = (pp / 3) * 2, sx = (pp % 3) * 2;
        float n0 = h2f(s2b[(sy * 6 + sx) * 128 + c0]) + h2f(s2b[(sy * 6 + sx + 1) * 128 + c0])
                 + h2f(s2b[((sy + 1) * 6 + sx) * 128 + c0]) + h2f(s2b[((sy + 1) * 6 + sx + 1) * 128 + c0]);
        int c1 = c0 + 1;
        float n1 = h2f(s2b[(sy * 6 + sx) * 128 + c1]) + h2f(s2b[(sy * 6 + sx + 1) * 128 + c1])
                 + h2f(s2b[((sy + 1) * 6 + sx) * 128 + c1]) + h2f(s2b[((sy + 1) * 6 + sx + 1) * 128 + c1]);
        unsigned bits = (unsigned)f2h_bits(0.25f * n0) | (((unsigned)f2h_bits(0.25f * n1)) << 16);
        p2g[(b * 100 + t) * 576 + tid] = bits;
      }
      __threadfence();
      __syncthreads();
      if (tid == 0)
        __hip_atomic_store(&flags[b * 100 + t], 1u, __ATOMIC_RELEASE, __HIP_MEMORY_SCOPE_AGENT);
    }
  } else {
    // ============== STAGE 2: conv3 + tc + rec + fc1 + fc2/acc ===============
    const int b = blockIdx.x - 32;
    const float4* w3p  = (const float4*)(ws + W3P_OFF);
    const float4* tcp  = (const float4*)(ws + TCP_OFF);
    const float4* recp = (const float4*)(ws + RECP_OFF);
    const float4* fc1p = (const float4*)(ws + FC1P_OFF);

    __shared__ __align__(16) float scratch[4096];
    __shared__ float p2L[1152];
    __shared__ unsigned short cidx[1152];
    __shared__ int ccnt[16];
    __shared__ float histf[768];
    __shared__ float s4v[256];
    __shared__ float c3cur[256], c3vol[256], c3sp[256];
    __shared__ float tccur[256], tcvol[256], tcsp[256];
    __shared__ float rcur[256],  rvol[256],  rsp[256];
    __shared__ float fcur[128],  fvol[128],  fsp[128];
    __shared__ float b3L[256], tcbL[768], recbL[256], fc1bL[128];
    __shared__ float fc2wL[256], maskL[128], tswL[100];
    __shared__ float accv[2];
    __shared__ float wpart[2][2];

    if (tid < 256) {
      c3sp[tid]  = c3sg[(0 * 32 + b) * 256 + tid];
      c3cur[tid] = c3sg[(1 * 32 + b) * 256 + tid];
      c3vol[tid] = c3sg[(2 * 32 + b) * 256 + tid];
      tcsp[tid]  = tcsg[(0 * 32 + b) * 256 + tid];
      tccur[tid] = tcsg[(1 * 32 + b) * 256 + tid];
      tcvol[tid] = tcsg[(2 * 32 + b) * 256 + tid];
      rsp[tid]   = rsg[(0 * 32 + b) * 256 + tid];
      rcur[tid]  = rsg[(1 * 32 + b) * 256 + tid];
      rvol[tid]  = rsg[(2 * 32 + b) * 256 + tid];
      b3L[tid]   = b3g[tid];
      recbL[tid] = recbg[tid];
      tcbL[tid]       = tcbg[tid];
      tcbL[256 + tid] = tcbg[256 + tid];
      tcbL[512 + tid] = tcbg[512 + tid];
      histf[tid] = 0.f; histf[256 + tid] = 0.f; histf[512 + tid] = 0.f;
    }
    if (tid < 128) {
      fsp[tid]   = fsg[(0 * 32 + b) * 128 + tid];
      fcur[tid]  = fsg[(1 * 32 + b) * 128 + tid];
      fvol[tid]  = fsg[(2 * 32 + b) * 128 + tid];
      fc1bL[tid] = fc1bg[tid];
      maskL[tid] = maskg[b * 128 + tid];
      fc2wL[tid]       = fc2wg[tid];
      fc2wL[128 + tid] = fc2wg[128 + tid];
    }
    if (tid < 100) tswL[tid] = tswg[tid];
    if (tid == 0) { accv[0] = 0.f; accv[1] = 0.f; }
    __syncthreads();

    for (int t = 0; t < 100; ++t) {
      const int tm3 = t % 3;

      // wait for producer (acquire)
      {
        unsigned* f = &flags[b * 100 + t];
        int guard = 0;
        while (__hip_atomic_load(f, __ATOMIC_ACQUIRE, __HIP_MEMORY_SCOPE_AGENT) == 0u) {
          __builtin_amdgcn_s_sleep(2);
          if (++guard > 400000) break;
        }
      }
      // load p2f
      if (tid < 576) {
        unsigned u = p2g[(b * 100 + t) * 576 + tid];
        p2L[2 * tid]     = h2f((unsigned short)(u & 0xffff));
        p2L[2 * tid + 1] = h2f((unsigned short)(u >> 16));
      }
      __syncthreads();

      // conv3: per-wave ballot compaction of 72-elem segment
      {
        int base = wv * 72;
        float e0 = p2L[base + ln];
        unsigned long long bl0 = __ballot(e0 != 0.f);
        if (e0 != 0.f)
          cidx[base + __popcll(bl0 & ((1ull << ln) - 1ull))] = (unsigned short)(base + ln);
        int cnt0 = __popcll(bl0);
        float e1 = (ln < 8) ? p2L[base + 64 + ln] : 0.f;
        unsigned long long bl1 = __ballot((ln < 8) && (e1 != 0.f));
        if (ln < 8 && e1 != 0.f)
          cidx[base + cnt0 + __popcll(bl1 & ((1ull << ln) - 1ull))] = (unsigned short)(base + 64 + ln);
        if (ln == 0) ccnt[wv] = cnt0 + __popcll(bl1);
      }
      __syncthreads();
      // conv3: branch-free compacted stream
      {
        int n = ccnt[wv], base = wv * 72;
        float4 a = {0.f, 0.f, 0.f, 0.f};
        int i = 0;
        for (; i + 2 <= n; i += 2) {
          int k0 = cidx[base + i], k1 = cidx[base + i + 1];
          float v0 = p2L[k0], v1 = p2L[k1];
          float4 w0 = w3p[k0 * 64 + ln];
          float4 w1 = w3p[k1 * 64 + ln];
          a.x = fmaf(v0, w0.x, a.x); a.y = fmaf(v0, w0.y, a.y);
          a.z = fmaf(v0, w0.z, a.z); a.w = fmaf(v0, w0.w, a.w);
          a.x = fmaf(v1, w1.x, a.x); a.y = fmaf(v1, w1.y, a.y);
          a.z = fmaf(v1, w1.z, a.z); a.w = fmaf(v1, w1.w, a.w);
        }
        if (i < n) {
          int k0 = cidx[base + i];
          float v0 = p2L[k0];
          float4 w0 = w3p[k0 * 64 + ln];
          a.x = fmaf(v0, w0.x, a.x); a.y = fmaf(v0, w0.y, a.y);
          a.z = fmaf(v0, w0.z, a.z); a.w = fmaf(v0, w0.w, a.w);
        }
        ((float4*)scratch)[tid] = a;
      }
      __syncthreads();
      // conv3 reduce + LIF3 -> hist ring
      if (tid < 256) {
        int d = tid;
        float s = b3L[d];
        #pragma unroll
        for (int ks = 0; ks < 16; ++ks) s += scratch[ks * 256 + d];
        float cur = 0.5f * c3cur[d] + s;
        float vol = 0.75f * c3vol[d] * (1.f - c3sp[d]) + cur;
        float sp  = (vol > VTH) ? 1.f : 0.f;
        c3cur[d] = cur; c3vol[d] = vol; c3sp[d] = sp;
        histf[tm3 * 256 + d] = sp;
      }
      __syncthreads();

      // tc: compaction of 48-elem segment (spike inputs, val == 1)
      {
        int kglob = wv * 48 + ln;
        float hv = 0.f;
        if (ln < 48) {
          int kk = kglob >> 8;
          int vvv = tm3 + 1 + kk; if (vvv >= 3) vvv -= 3;
          hv = histf[(vvv << 8) + (kglob & 255)];
        }
        unsigned long long bl0 = __ballot(hv != 0.f);
        if (hv != 0.f)
          cidx[wv * 48 + __popcll(bl0 & ((1ull << ln) - 1ull))] = (unsigned short)kglob;
        if (ln == 0) ccnt[wv] = __popcll(bl0);
      }
      __syncthreads();
      // tc: compacted stream (adds)
      {
        int n = ccnt[wv], base = wv * 48;
        float4 a = {0.f, 0.f, 0.f, 0.f};
        int i = 0;
        for (; i + 2 <= n; i += 2) {
          int k0 = cidx[base + i], k1 = cidx[base + i + 1];
          float4 w0 = tcp[k0 * 64 + ln];
          float4 w1 = tcp[k1 * 64 + ln];
          a.x += w0.x; a.y += w0.y; a.z += w0.z; a.w += w0.w;
          a.x += w1.x; a.y += w1.y; a.z += w1.z; a.w += w1.w;
        }
        if (i < n) {
          int k0 = cidx[base + i];
          float4 w0 = tcp[k0 * 64 + ln];
          a.x += w0.x; a.y += w0.y; a.z += w0.z; a.w += w0.w;
        }
        ((float4*)scratch)[tid] = a;
      }
      __syncthreads();
      // tc reduce + masked bias + LIF4 -> s4v
      if (tid < 256) {
        int d = tid;
        float s = 0.f;
        #pragma unroll
        for (int ks = 0; ks < 16; ++ks) s += scratch[ks * 256 + d];
        #pragma unroll
        for (int kk = 0; kk < 3; ++kk)
          if (t >= 2 - kk) s += tcbL[kk * 256 + d];
        float cur = 0.5f * tccur[d] + s;
        float vol = 0.75f * tcvol[d] * (1.f - tcsp[d]) + cur;
        float sp  = (vol > VTH) ? 1.f : 0.f;
        tccur[d] = cur; tcvol[d] = vol; tcsp[d] = sp;
        s4v[d] = sp;
      }
      __syncthreads();

      // rec: compaction of 16-elem segment (spike inputs)
      {
        float hv = (ln < 16) ? rsp[wv * 16 + ln] : 0.f;
        unsigned long long bl0 = __ballot(hv != 0.f);
        if (hv != 0.f)
          cidx[wv * 16 + __popcll(bl0 & ((1ull << ln) - 1ull))] = (unsigned short)(wv * 16 + ln);
        if (ln == 0) ccnt[wv] = __popcll(bl0);
      }
      __syncthreads();
      {
        int n = ccnt[wv], base = wv * 16;
        float4 a = {0.f, 0.f, 0.f, 0.f};
        for (int i = 0; i < n; ++i) {
          int k0 = cidx[base + i];
          float4 w0 = recp[k0 * 64 + ln];
          a.x += w0.x; a.y += w0.y; a.z += w0.z; a.w += w0.w;
        }
        ((float4*)scratch)[tid] = a;
      }
      __syncthreads();
      // rec reduce + LIF5 -> rsp
      if (tid < 256) {
        int d = tid;
        float s = s4v[d] + recbL[d];
        #pragma unroll
        for (int ks = 0; ks < 16; ++ks) s += scratch[ks * 256 + d];
        float cur = 0.5f * rcur[d] + s;
        float vol = 0.75f * rvol[d] * (1.f - rsp[d]) + cur;
        float sp  = (vol > VTH) ? 1.f : 0.f;
        rcur[d] = cur; rvol[d] = vol; rsp[d] = sp;
      }
      __syncthreads();

      // fc1 partials (K=256 split 32 ways, zero-skip as before)
      {
        int dq = tid & 31, ks = tid >> 5;
        float4 a = {0.f, 0.f, 0.f, 0.f};
        const float4* wrow = fc1p + (ks * 8) * 32 + dq;
        const float* hr = rsp + ks * 8;
        #pragma unroll
        for (int i = 0; i < 8; ++i) {
          float hv = hr[i];
          if (hv != 0.f) {
            float4 w = wrow[i * 32];
            a.x = fmaf(hv, w.x, a.x); a.y = fmaf(hv, w.y, a.y);
            a.z = fmaf(hv, w.z, a.z); a.w = fmaf(hv, w.w, a.w);
          }
        }
        ((float4*)scratch)[tid] = a;
      }
      __syncthreads();
      // fc1 reduce + dropout LIF6 + fc2 partial
      if (tid < 128) {
        int d = tid;
        float s = fc1bL[d];
        #pragma unroll
        for (int ks = 0; ks < 32; ++ks) s += scratch[ks * 128 + d];
        float cur = (0.5f * fcur[d] + s) * maskL[d];
        float vol = 0.75f * fvol[d] * (1.f - fsp[d]) + cur;
        float sp  = (vol > VTH) ? 1.f : 0.f;
        fcur[d] = cur; fvol[d] = vol; fsp[d] = sp;
        float v0 = sp * fc2wL[d];
        float v1 = sp * fc2wL[128 + d];
        #pragma unroll
        for (int off = 32; off > 0; off >>= 1) {
          v0 += __shfl_down(v0, off);
          v1 += __shfl_down(v1, off);
        }
        if ((tid & 63) == 0) { wpart[tid >> 6][0] = v0; wpart[tid >> 6][1] = v1; }
      }
      __syncthreads();
      if (tid == 0) {
        float wt = tswL[t];
        accv[0] += wt * (wpart[0][0] + wpart[1][0]);
        accv[1] += wt * (wpart[0][1] + wpart[1][1]);
      }
    }
    __syncthreads();
    if (tid < 2) out[b * 2 + tid] = accv[tid];
  }
}

// ---------------------------------------------------------------------------
// R7 monolithic fallback (used when ws_size < WS_NEED_BYTES)
// ---------------------------------------------------------------------------
__global__ __launch_bounds__(1024, 4) void snn_main(
    const float* __restrict__ input, const float* __restrict__ w1g,
    const float* __restrict__ b1g, const float* __restrict__ b2g,
    const float* __restrict__ b3g, const float* __restrict__ tcbg,
    const float* __restrict__ recbg, const float* __restrict__ fc1bg,
    const float* __restrict__ fc2wg, const float* __restrict__ tswg,
    const float* __restrict__ maskg,
    const float* __restrict__ c1sg, const float* __restrict__ c2sg,
    const float* __restrict__ c3sg, const float* __restrict__ tcsg,
    const float* __restrict__ rsg, const float* __restrict__ fsg,
    const float* __restrict__ ws, float* __restrict__ out)
{
  const half8v* w2h  = (const half8v*)ws;
  const float4* w3p  = (const float4*)(ws + W3P_OFF);
  const float4* tcp  = (const float4*)(ws + TCP_OFF);
  const float4* recp = (const float4*)(ws + RECP_OFF);
  const float4* fc1p = (const float4*)(ws + FC1P_OFF);

  const int b   = blockIdx.x;
  const int tid = threadIdx.x;
  const int wv  = tid >> 6;
  const int ln  = tid & 63;

  __shared__ __align__(16) float scratch[4096];
  __shared__ __align__(16) unsigned short s1b[84 * 64];
  __shared__ unsigned short s2b[36 * 128];
  __shared__ float p2f[1152];
  __shared__ float xt[100];
  __shared__ float histf[768];
  __shared__ float s4v[256];
  __shared__ float c3cur[256], c3vol[256], c3sp[256];
  __shared__ float tccur[256], tcvol[256], tcsp[256];
  __shared__ float rcur[256],  rvol[256],  rsp[256];
  __shared__ float fcur[128],  fvol[128],  fsp[128];
  __shared__ float b3L[256], tcbL[768], recbL[256], fc1bL[128];
  __shared__ float fc2wL[256], maskL[128], tswL[100], b2L[128];
  __shared__ float accv[2];
  __shared__ float wpart[2][2];

  const int co = ln, pos0 = wv;
  float w1r[9];
  #pragma unroll
  for (int k = 0; k < 9; ++k) w1r[k] = w1g[co * 9 + k];
  const float b1r = b1g[co];
  float sp1[4], cur1[4], vol1[4];
  #pragma unroll
  for (int j = 0; j < 4; ++j) {
    int pos = pos0 + 16 * j;
    sp1[j]  = c1sg[((0 * 32 + b) * 64 + co) * 64 + pos];
    cur1[j] = c1sg[((1 * 32 + b) * 64 + co) * 64 + pos];
    vol1[j] = c1sg[((2 * 32 + b) * 64 + co) * 64 + pos];
  }
  const int grpB = (wv < 8);
  const int nt2 = grpB ? wv : (wv - 8);
  const int mtA = grpB ? 0 : 2;
  const int mtB = 1;
  const int oc2 = nt2 * 16 + (ln & 15);
  int pybA, pybB;
  {
    int pA = mtA * 16 + (ln & 15);
    int pB = mtB * 16 + (ln & 15);
    pybA = (pA < 36) ? ((pA / 6) * 8 + (pA % 6)) : 64;
    pybB = (pB / 6) * 8 + (pB % 6);
  }
  float cur2[2][4], vol2[2][4];
  #pragma unroll
  for (int m = 0; m < 2; ++m) {
    int mt = m ? mtB : mtA;
    bool use = (m == 0) || grpB;
    #pragma unroll
    for (int r = 0; r < 4; ++r) {
      int p = mt * 16 + ((ln >> 4) << 2) + r;
      if (use && p < 36) {
        cur2[m][r] = c2sg[((1 * 32 + b) * 128 + oc2) * 36 + p];
        vol2[m][r] = c2sg[((2 * 32 + b) * 128 + oc2) * 36 + p];
      } else { cur2[m][r] = 0.f; vol2[m][r] = 0.f; }
    }
  }
  if (tid < 256) {
    c3sp[tid]  = c3sg[(0 * 32 + b) * 256 + tid];
    c3cur[tid] = c3sg[(1 * 32 + b) * 256 + tid];
    c3vol[tid] = c3sg[(2 * 32 + b) * 256 + tid];
    tcsp[tid]  = tcsg[(0 * 32 + b) * 256 + tid];
    tccur[tid] = tcsg[(1 * 32 + b) * 256 + tid];
    tcvol[tid] = tcsg[(2 * 32 + b) * 256 + tid];
    rsp[tid]   = rsg[(0 * 32 + b) * 256 + tid];
    rcur[tid]  = rsg[(1 * 32 + b) * 256 + tid];
    rvol[tid]  = rsg[(2 * 32 + b) * 256 + tid];
    b3L[tid]   = b3g[tid];
    recbL[tid] = recbg[tid];
    tcbL[tid]       = tcbg[tid];
    tcbL[256 + tid] = tcbg[256 + tid];
    tcbL[512 + tid] = tcbg[512 + tid];
    histf[tid] = 0.f; histf[256 + tid] = 0.f; histf[512 + tid] = 0.f;
  }
  if (tid < 128) {
    fsp[tid]   = fsg[(0 * 32 + b) * 128 + tid];
    fcur[tid]  = fsg[(1 * 32 + b) * 128 + tid];
    fvol[tid]  = fsg[(2 * 32 + b) * 128 + tid];
    fc1bL[tid] = fc1bg[tid];
    maskL[tid] = maskg[b * 128 + tid];
    b2L[tid]   = b2g[tid];
    fc2wL[tid]       = fc2wg[tid];
    fc2wL[128 + tid] = fc2wg[128 + tid];
  }
  if (tid < 100) tswL[tid] = tswg[tid];
  if (tid < 640) ((unsigned*)s1b)[64 * 32 + tid] = 0u;
  if (tid == 0) { accv[0] = 0.f; accv[1] = 0.f; }
  __syncthreads();

  for (int t = 0; t < 100; ++t) {
    const int tm3 = t % 3;
    if (tid < 100) xt[tid] = input[(b * 100 + tid) * 100 + t];
    __syncthreads();
    #pragma unroll
    for (int j = 0; j < 4; ++j) {
      int pos = pos0 + 16 * j;
      int y = pos >> 3, x = pos & 7;
      float psp = b1r;
      #pragma unroll
      for (int kk = 0; kk < 9; ++kk) {
        int ky = kk / 3, kx = kk - ky * 3;
        psp = fmaf(xt[(y + ky) * 10 + x + kx], w1r[kk], psp);
      }
      float cur = 0.5f * cur1[j] + psp;
      float vol = 0.75f * vol1[j] * (1.f - sp1[j]) + cur;
      float sp  = (vol > VTH) ? 1.f : 0.f;
      cur1[j] = cur; vol1[j] = vol; sp1[j] = sp;
      unsigned short bits = (vol > VTH) ? (unsigned short)0x3C00 : (unsigned short)0;
      int byte = ((pos << 7) + (co << 1)) ^ ((pos & 7) << 4);
      *(unsigned short*)((char*)s1b + byte) = bits;
    }
    __syncthreads();
    {
      f32x4 acchA = {0,0,0,0}, acclA = {0,0,0,0};
      f32x4 acchB = {0,0,0,0}, acclB = {0,0,0,0};
      const int lnq16 = (ln >> 4) << 4;
      if (grpB) {
        #pragma unroll
        for (int kt = 0; kt < 18; ++kt) {
          const int tap = kt >> 1;
          const int dpos = (tap / 3) * 8 + (tap % 3);
          const int c0b = ((kt & 1) << 6) + lnq16;
          int posA = pybA + dpos, posB = pybB + dpos;
          int abA = ((posA << 7) + c0b) ^ ((posA & 7) << 4);
          int abB = ((posB << 7) + c0b) ^ ((posB & 7) << 4);
          half8v a0 = *(const half8v*)((const char*)s1b + abA);
          half8v a1 = *(const half8v*)((const char*)s1b + abB);
          half8v bh = w2h[(((kt << 3) + nt2) << 1) * 64 + ln];
          half8v bl = w2h[((((kt << 3) + nt2) << 1) + 1) * 64 + ln];
          acchA = __builtin_amdgcn_mfma_f32_16x16x32_f16(a0, bh, acchA, 0, 0, 0);
          acclA = __builtin_amdgcn_mfma_f32_16x16x32_f16(a0, bl, acclA, 0, 0, 0);
          acchB = __builtin_amdgcn_mfma_f32_16x16x32_f16(a1, bh, acchB, 0, 0, 0);
          acclB = __builtin_amdgcn_mfma_f32_16x16x32_f16(a1, bl, acclB, 0, 0, 0);
        }
      } else {
        #pragma unroll
        for (int kt = 0; kt < 18; ++kt) {
          const int tap = kt >> 1;
          const int dpos = (tap / 3) * 8 + (tap % 3);
          const int c0b = ((kt & 1) << 6) + lnq16;
          int posA = pybA + dpos;
          int abA = ((posA << 7) + c0b) ^ ((posA & 7) << 4);
          half8v a0 = *(const half8v*)((const char*)s1b + abA);
          half8v bh = w2h[(((kt << 3) + nt2) << 1) * 64 + ln];
          half8v bl = w2h[((((kt << 3) + nt2) << 1) + 1) * 64 + ln];
          acchA = __builtin_amdgcn_mfma_f32_16x16x32_f16(a0, bh, acchA, 0, 0, 0);
          acclA = __builtin_amdgcn_mfma_f32_16x16x32_f16(a0, bl, acclA, 0, 0, 0);
        }
      }
      float bias2 = b2L[oc2];
      #pragma unroll
      for (int m = 0; m < 2; ++m) {
        if (m == 1 && !grpB) break;
        int mt = m ? mtB : mtA;
        #pragma unroll
        for (int r = 0; r < 4; ++r) {
          int p = mt * 16 + ((ln >> 4) << 2) + r;
          if (p < 36) {
            float hi = m ? acchB[r] : acchA[r];
            float lo = m ? acclB[r] : acclA[r];
            float psp = hi + 0.000244140625f * lo + bias2;
            float spo = (vol2[m][r] > VTH) ? 1.f : 0.f;
            float cur = 0.5f * cur2[m][r] + psp;
            float vol = 0.75f * vol2[m][r] * (1.f - spo) + cur;
            cur2[m][r] = cur; vol2[m][r] = vol;
            s2b[p * 128 + oc2] = (vol > VTH) ? (unsigned short)0x3C00 : (unsigned short)0;
          }
        }
      }
    }
    __syncthreads();
    {
      int c = tid & 127, pp = tid >> 7;
      int sy = (pp / 3) * 2, sx = (pp % 3) * 2;
      float v = h2f(s2b[(sy * 6 + sx) * 128 + c]) + h2f(s2b[(sy * 6 + sx + 1) * 128 + c])
              + h2f(s2b[((sy + 1) * 6 + sx) * 128 + c]) + h2f(s2b[((sy + 1) * 6 + sx + 1) * 128 + c]);
      p2f[pp * 128 + c] = 0.25f * v;
      if (tid < 128) {
        float v8 = h2f(s2b[(4 * 6 + 4) * 128 + c]) + h2f(s2b[(4 * 6 + 5) * 128 + c])
                 + h2f(s2b[(5 * 6 + 4) * 128 + c]) + h2f(s2b[(5 * 6 + 5) * 128 + c]);
        p2f[8 * 128 + c] = 0.25f * v8;
      }
    }
    __syncthreads();
    {
      int ocq = tid & 63, ks = tid >> 6;
      float4 a = {0.f, 0.f, 0.f, 0.f};
      const float4* wrow = w3p + (ks * 72) * 64 + ocq;
      const float* prow = p2f + ks * 72;
      #pragma unroll 8
      for (int i = 0; i < 72; ++i) {
        float pv = prow[i];
        if (pv != 0.f) {
          float4 w = wrow[i * 64];
          a.x = fmaf(pv, w.x, a.x); a.y = fmaf(pv, w.y, a.y);
          a.z = fmaf(pv, w.z, a.z); a.w = fmaf(pv, w.w, a.w);
        }
      }
      ((float4*)scratch)[tid] = a;
    }
    __syncthreads();
    if (tid < 256) {
      int d = tid;
      float s = b3L[d];
      #pragma unroll
      for (int ks = 0; ks < 16; ++ks) s += scratch[ks * 256 + d];
      float cur = 0.5f * c3cur[d] + s;
      float vol = 0.75f * c3vol[d] * (1.f - c3sp[d]) + cur;
      float sp  = (vol > VTH) ? 1.f : 0.f;
      c3cur[d] = cur; c3vol[d] = vol; c3sp[d] = sp;
      histf[tm3 * 256 + d] = sp;
    }
    __syncthreads();
    {
      int dq = tid & 63, ks = tid >> 6;
      float4 a = {0.f, 0.f, 0.f, 0.f};
      const float4* wrow = tcp + (ks * 48) * 64 + dq;
      #pragma unroll 8
      for (int i = 0; i < 48; ++i) {
        int k = ks * 48 + i;
        int kk = k >> 8;
        int vv = tm3 + 1 + kk; if (vv >= 3) vv -= 3;
        float hv = histf[(vv << 8) + (k & 255)];
        if (hv != 0.f) {
          float4 w = wrow[i * 64];
          a.x = fmaf(hv, w.x, a.x); a.y = fmaf(hv, w.y, a.y);
          a.z = fmaf(hv, w.z, a.z); a.w = fmaf(hv, w.w, a.w);
        }
      }
      ((float4*)scratch)[tid] = a;
    }
    __syncthreads();
    if (tid < 256) {
      int d = tid;
      float s = 0.f;
      #pragma unroll
      for (int ks = 0; ks < 16; ++ks) s += scratch[ks * 256 + d];
      #pragma unroll
      for (int kk = 0; kk < 3; ++kk)
        if (t >= 2 - kk) s += tcbL[kk * 256 + d];
      float cur = 0.5f * tccur[d] + s;
      float vol = 0.75f * tcvol[d] * (1.f - tcsp[d]) + cur;
      float sp  = (vol > VTH) ? 1.f : 0.f;
      tccur[d] = cur; tcvol[d] = vol; tcsp[d] = sp;
      s4v[d] = sp;
    }
    __syncthreads();
    {
      int dq = tid & 63, ks = tid >> 6;
      float4 a = {0.f, 0.f, 0.f, 0.f};
      const float4* wrow = recp + (ks * 16) * 64 + dq;
      const float* hr = rsp + ks * 16;
      #pragma unroll
      for (int i = 0; i < 16; ++i) {
        float hv = hr[i];
        if (hv != 0.f) {
          float4 w = wrow[i * 64];
          a.x = fmaf(hv, w.x, a.x); a.y = fmaf(hv, w.y, a.y);
          a.z = fmaf(hv, w.z, a.z); a.w = fmaf(hv, w.w, a.w);
        }
      }
      ((float4*)scratch)[tid] = a;
    }
    __syncthreads();
    if (tid < 256) {
      int d = tid;
      float s = s4v[d] + recbL[d];
      #pragma unroll
      for (int ks = 0; ks < 16; ++ks) s += scratch[ks * 256 + d];
      float cur = 0.5f * rcur[d] + s;
      float vol = 0.75f * rvol[d] * (1.f - rsp[d]) + cur;
      float sp  = (vol > VTH) ? 1.f : 0.f;
      rcur[d] = cur; rvol[d] = vol; rsp[d] = sp;
    }
    __syncthreads();
    {
      int dq = tid & 31, ks = tid >> 5;
      float4 a = {0.f, 0.f, 0.f, 0.f};
      const float4* wrow = fc1p + (ks * 8) * 32 + dq;
      const float* hr = rsp + ks * 8;
      #pragma unroll
      for (int i = 0; i < 8; ++i) {
        float hv = hr[i];
        if (hv != 0.f) {
          float4 w = wrow[i * 32];
          a.x = fmaf(hv, w.x, a.x); a.y = fmaf(hv, w.y, a.y);
          a.z = fmaf(hv, w.z, a.z); a.w = fmaf(hv, w.w, a.w);
        }
      }
      ((float4*)scratch)[tid] = a;
    }
    __syncthreads();
    if (tid < 128) {
      int d = tid;
      float s = fc1bL[d];
      #pragma unroll
      for (int ks = 0; ks < 32; ++ks) s += scratch[ks * 128 + d];
      float cur = (0.5f * fcur[d] + s) * maskL[d];
      float vol = 0.75f * fvol[d] * (1.f - fsp[d]) + cur;
      float sp  = (vol > VTH) ? 1.f : 0.f;
      fcur[d] = cur; fvol[d] = vol; fsp[d] = sp;
      float v0 = sp * fc2wL[d];
      float v1 = sp * fc2wL[128 + d];
      #pragma unroll
      for (int off = 32; off > 0; off >>= 1) {
        v0 += __shfl_down(v0, off);
        v1 += __shfl_down(v1, off);
      }
      if ((tid & 63) == 0) { wpart[tid >> 6][0] = v0; wpart[tid >> 6][1] = v1; }
    }
    __syncthreads();
    if (tid == 0) {
      float wt = tswL[t];
      accv[0] += wt * (wpart[0][0] + wpart[1][0]);
      accv[1] += wt * (wpart[0][1] + wpart[1][1]);
    }
  }
  __syncthreads();
  if (tid < 2) out[b * 2 + tid] = accv[tid];
}

extern "C" void kernel_launch(void* const* d_in, const int* in_sizes, int n_in,
                              void* d_out, int out_size, void* d_ws, size_t ws_size,
                              hipStream_t stream) {
  const float* input = (const float*)d_in[0];
  const float* w1    = (const float*)d_in[1];
  const float* b1    = (const float*)d_in[2];
  const float* w2    = (const float*)d_in[3];
  const float* b2    = (const float*)d_in[4];
  const float* w3    = (const float*)d_in[5];
  const float* b3    = (const float*)d_in[6];
  const float* tcw   = (const float*)d_in[7];
  const float* tcb   = (const float*)d_in[8];
  const float* recw  = (const float*)d_in[9];
  const float* recb  = (const float*)d_in[10];
  const float* fc1w  = (const float*)d_in[11];
  const float* fc1b  = (const float*)d_in[12];
  const float* fc2w  = (const float*)d_in[13];
  const float* tsw   = (const float*)d_in[14];
  const float* mask  = (const float*)d_in[15];
  const float* c1s   = (const float*)d_in[16];
  const float* c2s   = (const float*)d_in[17];
  const float* c3s   = (const float*)d_in[18];
  const float* tcs   = (const float*)d_in[19];
  const float* rs    = (const float*)d_in[20];
  const float* fs    = (const float*)d_in[21];
  float* ws   = (float*)d_ws;
  float* outp = (float*)d_out;

  prep_weights<<<WS_FLOATS / 256, 256, 0, stream>>>(w2, w3, tcw, recw, fc1w, ws);
  if (ws_size >= WS_NEED_BYTES) {
    zero_flags<<<(FLAGS_N + 255) / 256, 256, 0, stream>>>(ws);
    snn_pipe<<<64, 1024, 0, stream>>>(input, w1, b1, b2, b3, tcb, recb, fc1b,
                                      fc2w, tsw, mask, c1s, c2s, c3s, tcs, rs, fs,
                                      ws, outp);
  } else {
    snn_main<<<32, 1024, 0, stream>>>(input, w1, b1, b2, b3, tcb, recb, fc1b,
                                      fc2w, tsw, mask, c1s, c2s, c3s, tcs, rs, fs,
                                      ws, outp);
  }
}